// Round 3
// baseline (192.733 us; speedup 1.0000x reference)
//
#include <hip/hip_runtime.h>
#include <hip/hip_bf16.h>

// MoE adapter: out = x + sum_{e in top2} g_e * (relu(x@Wd[e]+bd[e]) @ Wu[e] + bu[e])
// B=8, L=2048, H=1024, E=8, R=256, top_k=2. fp32 in/out, bf16 MFMA compute.

typedef __attribute__((ext_vector_type(8))) short s8v;   // 8 bf16 = one MFMA A/B frag (4 VGPR)
typedef __attribute__((ext_vector_type(4))) short s4v;
typedef __attribute__((ext_vector_type(4))) float f4v;

constexpr int Bc = 8, Lc = 2048, Hc = 1024, Ec = 8, Rc = 256;
constexpr int TM = 64;      // token rows per block
constexpr int BK = 64;      // K step
constexpr int WPAD = 88;    // LDS row stride (bf16) for 64-wide tiles: 176B, 16B-aligned, bank-rotating
constexpr int HPAD = 280;   // LDS row stride (bf16) for h (256-wide): 560B, same properties

__device__ __forceinline__ unsigned short f2bf(float f) {
  unsigned int u = __float_as_uint(f);
  u += 0x7fffu + ((u >> 16) & 1u);   // round-to-nearest-even
  return (unsigned short)(u >> 16);
}

// ---------------- pooling (deterministic two-stage) ----------------
__global__ void pool_partial_kernel(const float* __restrict__ x, float* __restrict__ part) {
  // grid (B, 32): each block sums 64 rows of one batch over all H (float4 per thread)
  int b = blockIdx.x, lz = blockIdx.y;
  int h4 = threadIdx.x * 4;
  const float* xp = x + ((size_t)b * Lc + (size_t)lz * 64) * Hc + h4;
  f4v s; s[0] = 0.f; s[1] = 0.f; s[2] = 0.f; s[3] = 0.f;
  #pragma unroll 4
  for (int l = 0; l < 64; ++l) {
    f4v v = *reinterpret_cast<const f4v*>(xp + (size_t)l * Hc);
    s[0] += v[0]; s[1] += v[1]; s[2] += v[2]; s[3] += v[3];
  }
  *reinterpret_cast<f4v*>(&part[((size_t)b * 32 + lz) * Hc + h4]) = s;
}

__global__ void pool_reduce_kernel(const float* __restrict__ part, float* __restrict__ pooled) {
  int i = blockIdx.x * 256 + threadIdx.x;      // over B*H = 8192
  if (i >= Bc * Hc) return;
  int b = i >> 10, h = i & (Hc - 1);
  float s = 0.f;
  #pragma unroll 8
  for (int z = 0; z < 32; ++z) s += part[((size_t)b * 32 + z) * Hc + h];
  pooled[i] = s;
}

// ---------------- weight transpose + bf16 convert ----------------
// in: (E, M, N) fp32 -> out: (E, N, M) bf16
__global__ void transpose_kernel(const float* __restrict__ in, short* __restrict__ out,
                                 int M, int N) {
  __shared__ float t[32][33];
  int e = blockIdx.x;
  int m0 = blockIdx.y * 32, n0 = blockIdx.z * 32;
  const float* ine = in + (size_t)e * M * N;
  short* oute = out + (size_t)e * M * N;
  for (int i = threadIdx.y; i < 32; i += 8)
    t[i][threadIdx.x] = ine[(size_t)(m0 + i) * N + n0 + threadIdx.x];
  __syncthreads();
  for (int i = threadIdx.y; i < 32; i += 8)
    oute[(size_t)(n0 + i) * M + m0 + threadIdx.x] = (short)f2bf(t[threadIdx.x][i]);
}

// ---------------- gate: softmax(pooled @ Wr^T / L) + top-k ----------------
__global__ void gate_kernel(const float* __restrict__ pooled, const float* __restrict__ Wr,
                            const int* __restrict__ topk_p, float* __restrict__ gate,
                            int* __restrict__ sel, int* __restrict__ nsel) {
  __shared__ float logits[Bc * Ec];
  int tid = threadIdx.x, lane = tid & 63, wid = tid >> 6;
  for (int p = wid; p < Bc * Ec; p += 4) {
    int b = p >> 3, e = p & 7;
    float s = 0.f;
    for (int h = lane; h < Hc; h += 64) s += pooled[b * Hc + h] * Wr[e * Hc + h];
    for (int off = 32; off > 0; off >>= 1) s += __shfl_xor(s, off);
    if (lane == 0) logits[p] = s * (1.f / (float)Lc);
  }
  __syncthreads();
  if (tid < Bc) {
    int b = tid;
    float v[Ec];
    float mx = -1e30f;
    #pragma unroll
    for (int e = 0; e < Ec; ++e) { v[e] = logits[b * Ec + e]; mx = fmaxf(mx, v[e]); }
    float den = 0.f;
    #pragma unroll
    for (int e = 0; e < Ec; ++e) { v[e] = expf(v[e] - mx); den += v[e]; }
    #pragma unroll
    for (int e = 0; e < Ec; ++e) v[e] /= den;
    int K = *topk_p;
    if (K >= Ec) {
      #pragma unroll
      for (int e = 0; e < Ec; ++e) { gate[b * Ec + e] = v[e]; sel[b * Ec + e] = e; }
      nsel[b] = Ec;
    } else {
      float w[Ec];
      #pragma unroll
      for (int e = 0; e < Ec; ++e) { w[e] = v[e]; gate[b * Ec + e] = 0.f; }
      for (int i = 0; i < K; ++i) {           // selection: i-th largest, first index on ties
        int bj = 0; float bv = w[0];
        #pragma unroll
        for (int e = 1; e < Ec; ++e) if (w[e] > bv) { bv = w[e]; bj = e; }
        gate[b * Ec + bj] = v[bj];
        sel[b * Ec + i] = bj;
        w[bj] = -1.f;
      }
      nsel[b] = K;
    }
  }
}

// ---------------- fused expert kernel ----------------
// grid: 256 blocks, bid&7 = batch (XCD clustering), bid>>3 = token tile of 64 rows.
// 8 waves (2x4): each wave owns a 32x64 output sub-tile of each 64x256 GEMM stage.
__global__ __launch_bounds__(512, 2) void expert_kernel(
    const float* __restrict__ x, const float* __restrict__ bd, const float* __restrict__ bu,
    const short* __restrict__ Wdt, const short* __restrict__ Wut,
    const float* __restrict__ gate, const int* __restrict__ sel, const int* __restrict__ nselp,
    float* __restrict__ out)
{
  __shared__ short lA[TM * WPAD];        // x tile (bf16)            11.0 KB
  __shared__ short lB[Rc * WPAD];        // weight tile (bf16)       44.0 KB
  __shared__ short lh[2][TM * HPAD];     // g*relu(x@Wd+bd) per sel  70.0 KB

  const int bid = blockIdx.x;
  const int b = bid & 7;
  const int row0 = (bid >> 3) * TM;
  const int tid = threadIdx.x;
  const int lane = tid & 63;
  const int wid = tid >> 6;
  const int wr = wid >> 2, wc = wid & 3;
  const int lr = lane & 15;   // fragment row(A)/col(B,D) lane index
  const int lg = lane >> 4;   // k-group (A/B), row-group (D)

  const int nsel = nselp[b];
  const float* xb = x + (size_t)b * Lc * Hc;

  for (int base = 0; base < nsel; base += 2) {
    const int np = (nsel - base) >= 2 ? 2 : 1;

    // ---------- Phase A: h_s = g_s * relu(x @ Wd[e_s] + bd[e_s]) -> LDS ----------
    for (int s = 0; s < np; ++s) {
      const int e = sel[b * Ec + base + s];
      const float g = gate[b * Ec + e];
      const short* wd = Wdt + (size_t)e * Rc * Hc;   // (R, H) bf16
      f4v acc[2][4];
      #pragma unroll
      for (int m = 0; m < 2; ++m)
        #pragma unroll
        for (int n = 0; n < 4; ++n) acc[m][n] = 0.f;

      for (int kh = 0; kh < Hc; kh += BK) {
        __syncthreads();
        // stage x tile 64x64 fp32->bf16
        #pragma unroll
        for (int p = 0; p < 2; ++p) {
          int r = p * 32 + (tid >> 4);
          int c = (tid & 15) * 4;
          f4v v = *reinterpret_cast<const f4v*>(xb + (size_t)(row0 + r) * Hc + kh + c);
          s4v o;
          o[0] = (short)f2bf(v[0]); o[1] = (short)f2bf(v[1]);
          o[2] = (short)f2bf(v[2]); o[3] = (short)f2bf(v[3]);
          *reinterpret_cast<s4v*>(&lA[r * WPAD + c]) = o;
        }
        // stage Wd_t tile 256 x 64 (bf16, already K-contiguous)
        #pragma unroll
        for (int p = 0; p < 4; ++p) {
          int r = p * 64 + (tid >> 3);
          int c = (tid & 7) * 8;
          *reinterpret_cast<s8v*>(&lB[r * WPAD + c]) =
              *reinterpret_cast<const s8v*>(wd + (size_t)r * Hc + kh + c);
        }
        __syncthreads();
        #pragma unroll
        for (int kk = 0; kk < BK; kk += 32) {
          s8v af[2], bf[4];
          #pragma unroll
          for (int m = 0; m < 2; ++m)
            af[m] = *reinterpret_cast<const s8v*>(&lA[(wr * 32 + m * 16 + lr) * WPAD + kk + lg * 8]);
          #pragma unroll
          for (int n = 0; n < 4; ++n)
            bf[n] = *reinterpret_cast<const s8v*>(&lB[(wc * 64 + n * 16 + lr) * WPAD + kk + lg * 8]);
          #pragma unroll
          for (int m = 0; m < 2; ++m)
            #pragma unroll
            for (int n = 0; n < 4; ++n)
              acc[m][n] = __builtin_amdgcn_mfma_f32_16x16x32_bf16(af[m], bf[n], acc[m][n], 0, 0, 0);
        }
      }
      // epilogue: bias + relu + gate scale -> lh[s]   (C/D: col=lane&15, row=4*(lane>>4)+i)
      const float* bde = bd + e * Rc;
      #pragma unroll
      for (int n = 0; n < 4; ++n) {
        int cb = wc * 64 + n * 16 + lr;
        float bdv = bde[cb];
        #pragma unroll
        for (int m = 0; m < 2; ++m) {
          #pragma unroll
          for (int i = 0; i < 4; ++i) {
            int r = wr * 32 + m * 16 + lg * 4 + i;
            float vv = fmaxf(acc[m][n][i] + bdv, 0.f) * g;
            lh[s][r * HPAD + cb] = (short)f2bf(vv);
          }
        }
      }
    }

    // ---------- Phase B: out_chunk = x + sum_s h_s @ Wu[e_s] (+ gated bias) ----------
    for (int ch = 0; ch < 4; ++ch) {   // 4 chunks of 256 output columns
      f4v acc[2][4];
      #pragma unroll
      for (int m = 0; m < 2; ++m)
        #pragma unroll
        for (int n = 0; n < 4; ++n) acc[m][n] = 0.f;

      for (int s = 0; s < np; ++s) {
        const int e = sel[b * Ec + base + s];
        const short* wu = Wut + (size_t)e * Hc * Rc + (size_t)(ch * 256) * Rc;  // (H,R) bf16 slice
        for (int r0 = 0; r0 < Rc; r0 += BK) {
          __syncthreads();
          #pragma unroll
          for (int p = 0; p < 4; ++p) {
            int r = p * 64 + (tid >> 3);
            int c = (tid & 7) * 8;
            *reinterpret_cast<s8v*>(&lB[r * WPAD + c]) =
                *reinterpret_cast<const s8v*>(wu + (size_t)r * Rc + r0 + c);
          }
          __syncthreads();
          #pragma unroll
          for (int kk = 0; kk < BK; kk += 32) {
            s8v af[2], bf[4];
            #pragma unroll
            for (int m = 0; m < 2; ++m)
              af[m] = *reinterpret_cast<const s8v*>(
                  &lh[s][(wr * 32 + m * 16 + lr) * HPAD + r0 + kk + lg * 8]);
            #pragma unroll
            for (int n = 0; n < 4; ++n)
              bf[n] = *reinterpret_cast<const s8v*>(&lB[(wc * 64 + n * 16 + lr) * WPAD + kk + lg * 8]);
            #pragma unroll
            for (int m = 0; m < 2; ++m)
              #pragma unroll
              for (int n = 0; n < 4; ++n)
                acc[m][n] = __builtin_amdgcn_mfma_f32_16x16x32_bf16(af[m], bf[n], acc[m][n], 0, 0, 0);
          }
        }
      }
      // epilogue: residual + gated up-bias, write fp32
      #pragma unroll
      for (int n = 0; n < 4; ++n) {
        int cb = ch * 256 + wc * 64 + n * 16 + lr;
        float bias = 0.f;
        for (int s = 0; s < np; ++s) {
          int e = sel[b * Ec + base + s];
          bias += gate[b * Ec + e] * bu[e * Hc + cb];
        }
        #pragma unroll
        for (int m = 0; m < 2; ++m) {
          #pragma unroll
          for (int i = 0; i < 4; ++i) {
            int r = row0 + wr * 32 + m * 16 + lg * 4 + i;
            size_t idx = ((size_t)b * Lc + r) * Hc + cb;
            float vv = acc[m][n][i] + bias;
            out[idx] = (base == 0 ? x[idx] : out[idx]) + vv;
          }
        }
      }
    }
  }
}

extern "C" void kernel_launch(void* const* d_in, const int* in_sizes, int n_in,
                              void* d_out, int out_size, void* d_ws, size_t ws_size,
                              hipStream_t stream) {
  const float* x  = (const float*)d_in[0];
  const float* Wd = (const float*)d_in[1];
  const float* bd = (const float*)d_in[2];
  const float* Wu = (const float*)d_in[3];
  const float* bu = (const float*)d_in[4];
  const float* Wr = (const float*)d_in[5];
  const int* topk = (const int*)d_in[6];
  float* out = (float*)d_out;

  char* ws = (char*)d_ws;
  float* pooled = (float*)ws;                         // 32 KB
  float* gate   = (float*)(ws + 32768);               // 256 B
  int*   sel    = (int*)(ws + 33024);                 // 256 B
  int*   nsel   = (int*)(ws + 33280);                 // 32 B
  float* part   = (float*)(ws + 65536);               // (B,32,H) fp32 partials, 1 MB
  char*  wbase  = ws + 65536 + (size_t)Bc * 32 * Hc * 4;
  short* Wdt    = (short*)wbase;                                     // (E,R,H) bf16, 4 MB
  short* Wut    = (short*)(wbase + (size_t)Ec * Rc * Hc * 2);        // (E,H,R) bf16, 4 MB

  hipLaunchKernelGGL(pool_partial_kernel, dim3(Bc, 32), dim3(256), 0, stream, x, part);
  hipLaunchKernelGGL(transpose_kernel, dim3(Ec, Hc / 32, Rc / 32), dim3(32, 8), 0, stream,
                     Wd, Wdt, Hc, Rc);
  hipLaunchKernelGGL(transpose_kernel, dim3(Ec, Rc / 32, Hc / 32), dim3(32, 8), 0, stream,
                     Wu, Wut, Rc, Hc);
  hipLaunchKernelGGL(pool_reduce_kernel, dim3((Bc * Hc + 255) / 256), dim3(256), 0, stream,
                     part, pooled);
  hipLaunchKernelGGL(gate_kernel, dim3(1), dim3(256), 0, stream,
                     pooled, Wr, topk, gate, sel, nsel);
  hipLaunchKernelGGL(expert_kernel, dim3(Bc * (Lc / TM)), dim3(512), 0, stream,
                     x, bd, bu, Wdt, Wut, gate, sel, nsel, out);
}

// Round 4
// 146.095 us; speedup vs baseline: 1.3192x; 1.3192x over previous
//
#include <hip/hip_runtime.h>
#include <hip/hip_bf16.h>

// MoE adapter: out = x + sum_{e in top2} g_e * (relu(x@Wd[e]+bd[e]) @ Wu[e] + bu[e])
// B=8, L=2048, H=1024, E=8, R=256, top_k=2 (pipeline assumes top_k==2, as in setup).
// Split design: pre-tiled bf16 weights -> GEMM1 (h, gate-folded) -> GEMM2 (+residual).

typedef __attribute__((ext_vector_type(8))) short s8v;
typedef __attribute__((ext_vector_type(4))) short s4v;
typedef __attribute__((ext_vector_type(4))) float f4v;

constexpr int Bc = 8, Lc = 2048, Hc = 1024, Ec = 8, Rc = 256;

__device__ __forceinline__ unsigned short f2bf(float f) {
  unsigned int u = __float_as_uint(f);
  u += 0x7fffu + ((u >> 16) & 1u);   // RNE
  return (unsigned short)(u >> 16);
}

typedef __attribute__((address_space(1))) const unsigned int ga_u32;
typedef __attribute__((address_space(3))) unsigned int ls_u32;
__device__ __forceinline__ void gload_lds16(const void* g, void* l) {
  __builtin_amdgcn_global_load_lds((ga_u32*)g, (ls_u32*)l, 16, 0, 0);
}

// ---------------- pooling (deterministic two-stage) ----------------
__global__ void pool_partial_kernel(const float* __restrict__ x, float* __restrict__ part) {
  int b = blockIdx.x, lz = blockIdx.y;
  int h4 = threadIdx.x * 4;
  const float* xp = x + ((size_t)b * Lc + (size_t)lz * 64) * Hc + h4;
  f4v s; s[0] = 0.f; s[1] = 0.f; s[2] = 0.f; s[3] = 0.f;
  #pragma unroll 4
  for (int l = 0; l < 64; ++l) {
    f4v v = *reinterpret_cast<const f4v*>(xp + (size_t)l * Hc);
    s[0] += v[0]; s[1] += v[1]; s[2] += v[2]; s[3] += v[3];
  }
  *reinterpret_cast<f4v*>(&part[((size_t)b * 32 + lz) * Hc + h4]) = s;
}

__global__ void pool_reduce_kernel(const float* __restrict__ part, float* __restrict__ pooled) {
  int i = blockIdx.x * 256 + threadIdx.x;
  if (i >= Bc * Hc) return;
  int b = i >> 10, h = i & (Hc - 1);
  float s = 0.f;
  #pragma unroll 8
  for (int z = 0; z < 32; ++z) s += part[((size_t)b * 32 + z) * Hc + h];
  pooled[i] = s;
}

// ---------------- weight tiling: fp32 (Rows x Cols) -> bf16 fragment image ----------------
// dst chunk ((e*NCT+ct)*NRT+rt) = [kg(8)][c(CT)][j(8)], src row = rt*64+kg*8+j, col = ct*CT+c.
template<int CT>
__global__ void tile_weight_kernel(const float* __restrict__ src, short* __restrict__ dst,
                                   int Rows, int Cols, int NRT, int NCT) {
  __shared__ short t[64][CT + 8];
  const int e = blockIdx.x, rt = blockIdx.y, ct = blockIdx.z;
  const int tid = threadIdx.x;
  const float* se = src + (size_t)e * Rows * Cols + (size_t)(rt * 64) * Cols + ct * CT;
  for (int idx = tid; idx < 64 * CT / 4; idx += 256) {
    int rr = idx / (CT / 4), c4 = (idx % (CT / 4)) * 4;
    f4v v = *reinterpret_cast<const f4v*>(se + (size_t)rr * Cols + c4);
    s4v o; o[0] = (short)f2bf(v[0]); o[1] = (short)f2bf(v[1]);
    o[2] = (short)f2bf(v[2]); o[3] = (short)f2bf(v[3]);
    *reinterpret_cast<s4v*>(&t[rr][c4]) = o;
  }
  __syncthreads();
  short* de = dst + ((size_t)(e * NCT + ct) * NRT + rt) * (64 * CT);
  for (int gi = tid; gi < 64 * CT / 8; gi += 256) {
    int kg = gi / CT, c = gi % CT;
    s8v o;
    #pragma unroll
    for (int j = 0; j < 8; ++j) o[j] = t[kg * 8 + j][c];
    *reinterpret_cast<s8v*>(de + (size_t)gi * 8) = o;
  }
}

// ---------------- gate: softmax(pooled @ Wr^T / L) + top-k ----------------
__global__ void gate_kernel(const float* __restrict__ pooled, const float* __restrict__ Wr,
                            const int* __restrict__ topk_p, float* __restrict__ gate,
                            int* __restrict__ sel, int* __restrict__ nsel) {
  __shared__ float logits[Bc * Ec];
  int tid = threadIdx.x, lane = tid & 63, wid = tid >> 6;
  for (int p = wid; p < Bc * Ec; p += 4) {
    int b = p >> 3, e = p & 7;
    float s = 0.f;
    for (int h = lane; h < Hc; h += 64) s += pooled[b * Hc + h] * Wr[e * Hc + h];
    for (int off = 32; off > 0; off >>= 1) s += __shfl_xor(s, off);
    if (lane == 0) logits[p] = s * (1.f / (float)Lc);
  }
  __syncthreads();
  if (tid < Bc) {
    int b = tid;
    float v[Ec];
    float mx = -1e30f;
    #pragma unroll
    for (int e = 0; e < Ec; ++e) { v[e] = logits[b * Ec + e]; mx = fmaxf(mx, v[e]); }
    float den = 0.f;
    #pragma unroll
    for (int e = 0; e < Ec; ++e) { v[e] = expf(v[e] - mx); den += v[e]; }
    #pragma unroll
    for (int e = 0; e < Ec; ++e) v[e] /= den;
    int K = *topk_p;
    if (K > 2) K = 2;    // pipeline supports 2 slots (bench uses top_k=2)
    float w[Ec];
    #pragma unroll
    for (int e = 0; e < Ec; ++e) { w[e] = v[e]; gate[b * Ec + e] = 0.f; }
    for (int i = 0; i < K; ++i) {
      int bj = 0; float bv = w[0];
      #pragma unroll
      for (int e = 1; e < Ec; ++e) if (w[e] > bv) { bv = w[e]; bj = e; }
      gate[b * Ec + bj] = v[bj];
      sel[b * Ec + i] = bj;
      w[bj] = -1.f;
    }
    nsel[b] = K;
  }
}

// ---------------- GEMM1: h[b,mt,s] = g * relu(x @ Wd[e_s] + bd) -> ht (bf16, tiled) ----------
// grid 512: bid = (mt*2+s)*8 + b. 64x256 tile, K=1024, 8 waves (2x4), dbuf, 2 blocks/CU.
__global__ __launch_bounds__(512, 4) void gemm1_kernel(
    const float* __restrict__ x, const float* __restrict__ bd,
    const short* __restrict__ Wdt, const float* __restrict__ gate,
    const int* __restrict__ sel, short* __restrict__ ht) {
  __shared__ short sA[2][4096];    // XOR-swizzled [r(64)][kg(8)x8] image, 8KB each
  __shared__ short sB[2][16384];   // [kg(8)][r(256)][j(8)] image, 32KB each

  const int bid = blockIdx.x;
  const int b = bid & 7, q = bid >> 3;
  const int mt = q >> 1, s = q & 1;
  const int e = sel[b * Ec + s];
  const float g = gate[b * Ec + e];
  const int tid = threadIdx.x, lane = tid & 63, wid = tid >> 6;
  const int wr = wid >> 2, wc = wid & 3, lr = lane & 15, lg = lane >> 4;
  const float* xb = x + ((size_t)b * Lc + mt * 64) * Hc;
  const short* wdt = Wdt + (size_t)e * (Rc * Hc);
  const int sr = tid >> 3, skg = tid & 7;
  const int aw_off = sr * 64 + ((skg * 8) ^ ((sr & 7) * 8));   // shorts

  f4v acc[2][4];
  #pragma unroll
  for (int m = 0; m < 2; ++m)
    #pragma unroll
    for (int n = 0; n < 4; ++n) { acc[m][n][0]=0.f; acc[m][n][1]=0.f; acc[m][n][2]=0.f; acc[m][n][3]=0.f; }

  // prologue: stage kt=0
  {
    const short* gsrc = wdt;      // kt=0
    #pragma unroll
    for (int p = 0; p < 4; ++p)
      gload_lds16(gsrc + (p * 512 + tid) * 8, &sB[0][(p * 512 + tid) * 8]);
    f4v v0 = *reinterpret_cast<const f4v*>(xb + (size_t)sr * Hc + skg * 8);
    f4v v1 = *reinterpret_cast<const f4v*>(xb + (size_t)sr * Hc + skg * 8 + 4);
    s8v o;
    o[0]=(short)f2bf(v0[0]); o[1]=(short)f2bf(v0[1]); o[2]=(short)f2bf(v0[2]); o[3]=(short)f2bf(v0[3]);
    o[4]=(short)f2bf(v1[0]); o[5]=(short)f2bf(v1[1]); o[6]=(short)f2bf(v1[2]); o[7]=(short)f2bf(v1[3]);
    *reinterpret_cast<s8v*>(&sA[0][aw_off]) = o;
  }
  __syncthreads();

  for (int kt = 0; kt < 16; ++kt) {
    const int cur = kt & 1, nxt = cur ^ 1;
    f4v nv0, nv1;
    if (kt < 15) {
      const short* gsrc = wdt + (kt + 1) * 16384;
      #pragma unroll
      for (int p = 0; p < 4; ++p)
        gload_lds16(gsrc + (p * 512 + tid) * 8, &sB[nxt][(p * 512 + tid) * 8]);
      nv0 = *reinterpret_cast<const f4v*>(xb + (size_t)sr * Hc + (kt + 1) * 64 + skg * 8);
      nv1 = *reinterpret_cast<const f4v*>(xb + (size_t)sr * Hc + (kt + 1) * 64 + skg * 8 + 4);
    }
    #pragma unroll
    for (int kk = 0; kk < 2; ++kk) {
      s8v af[2], bf[4];
      #pragma unroll
      for (int m = 0; m < 2; ++m) {
        int r = wr * 32 + m * 16 + lr;
        af[m] = *reinterpret_cast<const s8v*>(&sA[cur][r * 64 + (((kk * 4 + lg) * 8) ^ ((r & 7) * 8))]);
      }
      #pragma unroll
      for (int n = 0; n < 4; ++n) {
        int c = wc * 64 + n * 16 + lr;
        bf[n] = *reinterpret_cast<const s8v*>(&sB[cur][((kk * 4 + lg) * 256 + c) * 8]);
      }
      #pragma unroll
      for (int m = 0; m < 2; ++m)
        #pragma unroll
        for (int n = 0; n < 4; ++n)
          acc[m][n] = __builtin_amdgcn_mfma_f32_16x16x32_bf16(af[m], bf[n], acc[m][n], 0, 0, 0);
    }
    if (kt < 15) {
      s8v o;
      o[0]=(short)f2bf(nv0[0]); o[1]=(short)f2bf(nv0[1]); o[2]=(short)f2bf(nv0[2]); o[3]=(short)f2bf(nv0[3]);
      o[4]=(short)f2bf(nv1[0]); o[5]=(short)f2bf(nv1[1]); o[6]=(short)f2bf(nv1[2]); o[7]=(short)f2bf(nv1[3]);
      *reinterpret_cast<s8v*>(&sA[nxt][aw_off]) = o;
    }
    __syncthreads();
  }

  // epilogue: bias + relu + gate, repack to GEMM2 A-image, write ht
  short* rp = &sB[0][0];   // 16384 shorts, safe after final barrier
  const float* bde = bd + e * Rc;
  #pragma unroll
  for (int n = 0; n < 4; ++n) {
    int c = wc * 64 + n * 16 + lr;
    float bdv = bde[c];
    #pragma unroll
    for (int m = 0; m < 2; ++m)
      #pragma unroll
      for (int i = 0; i < 4; ++i) {
        int rr = wr * 32 + m * 16 + lg * 4 + i;
        float vv = fmaxf(acc[m][n][i] + bdv, 0.f) * g;
        rp[((c >> 3) * 64 + rr) * 8 + (c & 7)] = (short)f2bf(vv);
      }
  }
  __syncthreads();
  const int mt2 = mt >> 1, rbase = (mt & 1) * 64;
  short* hb = ht + (((size_t)b * 16 + mt2) * 8 + s * 4) * 8192;
  #pragma unroll
  for (int p = 0; p < 4; ++p) {
    int gi = p * 512 + tid;
    int ftl = gi >> 9, kg = (gi >> 6) & 7, rr = gi & 63;
    s8v v = *reinterpret_cast<const s8v*>(&rp[gi * 8]);
    *reinterpret_cast<s8v*>(hb + (((size_t)ftl * 8 + kg) * 128 + rbase + rr) * 8) = v;
  }
}

// ---------------- GEMM2: out = x + h_concat @ Wu_concat + sum g*bu ----------------
// grid 1024: bid = ((mt2*8+nt))*8 + b. 128x128 tile, K=512 (2 experts concat), dbuf, 2 blocks/CU.
__global__ __launch_bounds__(512, 4) void gemm2_kernel(
    const float* __restrict__ x, const float* __restrict__ bu,
    const short* __restrict__ ht, const short* __restrict__ Wut2,
    const float* __restrict__ gate, const int* __restrict__ sel,
    float* __restrict__ out) {
  __shared__ short sA[2][8192];   // [kg(8)][r(128)][j(8)]
  __shared__ short sB[2][8192];   // [kg(8)][c(128)][j(8)]

  const int bid = blockIdx.x;
  const int b = bid & 7, q = bid >> 3;
  const int mt2 = q >> 3, nt = q & 7;
  const int e0 = sel[b * Ec], e1 = sel[b * Ec + 1];
  const float g0 = gate[b * Ec + e0], g1 = gate[b * Ec + e1];
  const int tid = threadIdx.x, lane = tid & 63, wid = tid >> 6;
  const int wr = wid >> 2, wc = wid & 3, lr = lane & 15, lg = lane >> 4;
  const short* ab = ht + ((size_t)b * 16 + mt2) * 65536;

  f4v acc[4][2];
  #pragma unroll
  for (int m = 0; m < 4; ++m)
    #pragma unroll
    for (int n = 0; n < 2; ++n) { acc[m][n][0]=0.f; acc[m][n][1]=0.f; acc[m][n][2]=0.f; acc[m][n][3]=0.f; }

  // prologue: stage ft=0
  {
    const short* ga = ab;
    const short* gb = Wut2 + (((size_t)e0 * 8 + nt) * 4 + 0) * 8192;
    #pragma unroll
    for (int p = 0; p < 2; ++p) {
      gload_lds16(ga + (p * 512 + tid) * 8, &sA[0][(p * 512 + tid) * 8]);
      gload_lds16(gb + (p * 512 + tid) * 8, &sB[0][(p * 512 + tid) * 8]);
    }
  }
  __syncthreads();

  for (int ft = 0; ft < 8; ++ft) {
    const int cur = ft & 1, nxt = cur ^ 1;
    if (ft < 7) {
      const int f2 = ft + 1;
      const short* ga = ab + f2 * 8192;
      const int ee = (f2 < 4) ? e0 : e1;
      const short* gb = Wut2 + (((size_t)ee * 8 + nt) * 4 + (f2 & 3)) * 8192;
      #pragma unroll
      for (int p = 0; p < 2; ++p) {
        gload_lds16(ga + (p * 512 + tid) * 8, &sA[nxt][(p * 512 + tid) * 8]);
        gload_lds16(gb + (p * 512 + tid) * 8, &sB[nxt][(p * 512 + tid) * 8]);
      }
    }
    #pragma unroll
    for (int kk = 0; kk < 2; ++kk) {
      s8v af[4], bf[2];
      #pragma unroll
      for (int m = 0; m < 4; ++m) {
        int r = wr * 64 + m * 16 + lr;
        af[m] = *reinterpret_cast<const s8v*>(&sA[cur][((kk * 4 + lg) * 128 + r) * 8]);
      }
      #pragma unroll
      for (int n = 0; n < 2; ++n) {
        int c = wc * 32 + n * 16 + lr;
        bf[n] = *reinterpret_cast<const s8v*>(&sB[cur][((kk * 4 + lg) * 128 + c) * 8]);
      }
      #pragma unroll
      for (int m = 0; m < 4; ++m)
        #pragma unroll
        for (int n = 0; n < 2; ++n)
          acc[m][n] = __builtin_amdgcn_mfma_f32_16x16x32_bf16(af[m], bf[n], acc[m][n], 0, 0, 0);
    }
    __syncthreads();
  }

  // epilogue: residual + gated up-bias
  const int R0 = mt2 * 128 + wr * 64, C0 = nt * 128 + wc * 32;
  #pragma unroll
  for (int n = 0; n < 2; ++n) {
    int C = C0 + n * 16 + lr;
    float bias = g0 * bu[e0 * Hc + C] + g1 * bu[e1 * Hc + C];
    #pragma unroll
    for (int m = 0; m < 4; ++m)
      #pragma unroll
      for (int i = 0; i < 4; ++i) {
        int R = R0 + m * 16 + lg * 4 + i;
        size_t idx = ((size_t)b * Lc + R) * Hc + C;
        out[idx] = x[idx] + acc[m][n][i] + bias;
      }
  }
}

extern "C" void kernel_launch(void* const* d_in, const int* in_sizes, int n_in,
                              void* d_out, int out_size, void* d_ws, size_t ws_size,
                              hipStream_t stream) {
  const float* x  = (const float*)d_in[0];
  const float* Wd = (const float*)d_in[1];
  const float* bd = (const float*)d_in[2];
  const float* Wu = (const float*)d_in[3];
  const float* bu = (const float*)d_in[4];
  const float* Wr = (const float*)d_in[5];
  const int* topk = (const int*)d_in[6];
  float* out = (float*)d_out;

  char* ws = (char*)d_ws;
  float* pooled = (float*)ws;                          // 32 KB
  float* gate   = (float*)(ws + 32768);                // 256 B
  int*   sel    = (int*)(ws + 33024);                  // 256 B
  int*   nsel   = (int*)(ws + 33280);                  // 32 B
  float* part   = (float*)(ws + 65536);                // 1 MB (8*32*1024 f32)
  char*  p1     = ws + 65536 + (size_t)Bc * 32 * Hc * 4;
  short* Wdt    = (short*)p1;                          // 4 MB  (E*H*R bf16, tiled)
  short* Wut2   = (short*)(p1 + (size_t)Ec * Hc * Rc * 2);   // 4 MB (tiled)
  short* ht     = (short*)(p1 + (size_t)Ec * Hc * Rc * 4);   // 16 MB (B*L*512 bf16, tiled)

  hipLaunchKernelGGL(pool_partial_kernel, dim3(Bc, 32), dim3(256), 0, stream, x, part);
  // Wd (E,1024,256): Rows=1024, Cols=256, CT=256, NRT=16, NCT=1
  hipLaunchKernelGGL((tile_weight_kernel<256>), dim3(Ec, 16, 1), dim3(256), 0, stream,
                     Wd, Wdt, Hc, Rc, 16, 1);
  // Wu (E,256,1024): Rows=256, Cols=1024, CT=128, NRT=4, NCT=8
  hipLaunchKernelGGL((tile_weight_kernel<128>), dim3(Ec, 4, 8), dim3(256), 0, stream,
                     Wu, Wut2, Rc, Hc, 4, 8);
  hipLaunchKernelGGL(pool_reduce_kernel, dim3((Bc * Hc + 255) / 256), dim3(256), 0, stream,
                     part, pooled);
  hipLaunchKernelGGL(gate_kernel, dim3(1), dim3(256), 0, stream,
                     pooled, Wr, topk, gate, sel, nsel);
  hipLaunchKernelGGL(gemm1_kernel, dim3(512), dim3(512), 0, stream,
                     x, bd, Wdt, gate, sel, ht);
  hipLaunchKernelGGL(gemm2_kernel, dim3(1024), dim3(512), 0, stream,
                     x, bu, ht, Wut2, gate, sel, out);
}

// Round 5
// 94.197 us; speedup vs baseline: 2.0461x; 1.5510x over previous
//
#include <hip/hip_runtime.h>
#include <hip/hip_bf16.h>

// MoE adapter: out = x + sum_{e in top2} g_e * (relu(x@Wd[e]+bd[e]) @ Wu[e] + bu[e])
// B=8, L=2048, H=1024, E=8, R=256, top_k=2 (pipeline supports up to 2 slots).
// Split design: pre-tiled bf16 weights -> GEMM1 (h, gate-folded) -> GEMM2 (+residual).

typedef __attribute__((ext_vector_type(8))) short s8v;
typedef __attribute__((ext_vector_type(4))) short s4v;
typedef __attribute__((ext_vector_type(4))) float f4v;

constexpr int Bc = 8, Lc = 2048, Hc = 1024, Ec = 8, Rc = 256;

__device__ __forceinline__ unsigned short f2bf(float f) {
  unsigned int u = __float_as_uint(f);
  u += 0x7fffu + ((u >> 16) & 1u);   // RNE
  return (unsigned short)(u >> 16);
}

typedef __attribute__((address_space(1))) const unsigned int ga_u32;
typedef __attribute__((address_space(3))) unsigned int ls_u32;
__device__ __forceinline__ void gload_lds16(const void* g, void* l) {
  __builtin_amdgcn_global_load_lds((ga_u32*)g, (ls_u32*)l, 16, 0, 0);
}

// ---------------- pooling stage 1: per-(b, 64-row chunk) partial sums ----------------
__global__ void pool_partial_kernel(const float* __restrict__ x, float* __restrict__ part) {
  int b = blockIdx.x, lz = blockIdx.y;
  int h4 = threadIdx.x * 4;
  const float* xp = x + ((size_t)b * Lc + (size_t)lz * 64) * Hc + h4;
  f4v s; s[0] = 0.f; s[1] = 0.f; s[2] = 0.f; s[3] = 0.f;
  #pragma unroll 4
  for (int l = 0; l < 64; ++l) {
    f4v v = *reinterpret_cast<const f4v*>(xp + (size_t)l * Hc);
    s[0] += v[0]; s[1] += v[1]; s[2] += v[2]; s[3] += v[3];
  }
  *reinterpret_cast<f4v*>(&part[((size_t)b * 32 + lz) * Hc + h4]) = s;
}

// ---------------- logits: fused z-reduce + Wr dot. grid 64 = (b,e) ----------------
__global__ void logits_kernel(const float* __restrict__ part, const float* __restrict__ Wr,
                              float* __restrict__ logits) {
  __shared__ float red[4];
  const int b = blockIdx.x >> 3, e = blockIdx.x & 7;
  const int t = threadIdx.x, lane = t & 63, wid = t >> 6;
  const int h4 = t * 4;
  f4v w = *reinterpret_cast<const f4v*>(Wr + (size_t)e * Hc + h4);
  f4v s; s[0] = 0.f; s[1] = 0.f; s[2] = 0.f; s[3] = 0.f;
  const float* pb = part + (size_t)b * 32 * Hc + h4;
  #pragma unroll 8
  for (int z = 0; z < 32; ++z) {
    f4v v = *reinterpret_cast<const f4v*>(pb + (size_t)z * Hc);
    s[0] += v[0] * w[0]; s[1] += v[1] * w[1]; s[2] += v[2] * w[2]; s[3] += v[3] * w[3];
  }
  float d = (s[0] + s[1]) + (s[2] + s[3]);
  #pragma unroll
  for (int off = 32; off > 0; off >>= 1) d += __shfl_xor(d, off);
  if (lane == 0) red[wid] = d;
  __syncthreads();
  if (t == 0) logits[blockIdx.x] = (red[0] + red[1] + red[2] + red[3]) * (1.f / (float)Lc);
}

// ---------------- softmax + top-k -> per-slot (gate, expert) ----------------
__global__ void softmax_topk_kernel(const float* __restrict__ logits, const int* __restrict__ topk_p,
                                    float* __restrict__ gslot, int* __restrict__ sel2) {
  int b = threadIdx.x;
  if (b >= Bc) return;
  float v[Ec];
  float mx = -1e30f;
  #pragma unroll
  for (int e = 0; e < Ec; ++e) { v[e] = logits[b * Ec + e]; mx = fmaxf(mx, v[e]); }
  float den = 0.f;
  #pragma unroll
  for (int e = 0; e < Ec; ++e) { v[e] = expf(v[e] - mx); den += v[e]; }
  #pragma unroll
  for (int e = 0; e < Ec; ++e) v[e] /= den;
  int K = *topk_p;
  if (K > 2) K = 2;                 // pipeline supports 2 slots (bench uses top_k=2)
  float w[Ec];
  #pragma unroll
  for (int e = 0; e < Ec; ++e) w[e] = v[e];
  int prev = 0;
  for (int i = 0; i < 2; ++i) {
    if (i < K) {
      int bj = 0; float bv = w[0];
      #pragma unroll
      for (int e = 1; e < Ec; ++e) if (w[e] > bv) { bv = w[e]; bj = e; }
      gslot[b * 2 + i] = v[bj];
      sel2[b * 2 + i] = bj;
      w[bj] = -1.f;
      prev = bj;
    } else {                         // unused slot: zero gate, harmless expert index
      gslot[b * 2 + i] = 0.f;
      sel2[b * 2 + i] = prev;
    }
  }
}

// ---------------- weight tiling: fp32 (Rows x Cols) -> bf16 fragment image ----------------
// dst chunk ((e*NCT+ct)*NRT+rt) = [kg(8)][c(CT)][j(8)], src row = rt*64+kg*8+j, col = ct*CT+c.
template<int CT>
__global__ void tile_weight_kernel(const float* __restrict__ src, short* __restrict__ dst,
                                   int Rows, int Cols, int NRT, int NCT) {
  __shared__ short t[64][CT + 8];
  const int e = blockIdx.x, rt = blockIdx.y, ct = blockIdx.z;
  const int tid = threadIdx.x;
  const float* se = src + (size_t)e * Rows * Cols + (size_t)(rt * 64) * Cols + ct * CT;
  for (int idx = tid; idx < 64 * CT / 4; idx += 256) {
    int rr = idx / (CT / 4), c4 = (idx % (CT / 4)) * 4;
    f4v v = *reinterpret_cast<const f4v*>(se + (size_t)rr * Cols + c4);
    s4v o; o[0] = (short)f2bf(v[0]); o[1] = (short)f2bf(v[1]);
    o[2] = (short)f2bf(v[2]); o[3] = (short)f2bf(v[3]);
    *reinterpret_cast<s4v*>(&t[rr][c4]) = o;
  }
  __syncthreads();
  short* de = dst + ((size_t)(e * NCT + ct) * NRT + rt) * (64 * CT);
  for (int gi = tid; gi < 64 * CT / 8; gi += 256) {
    int kg = gi / CT, c = gi % CT;
    s8v o;
    #pragma unroll
    for (int j = 0; j < 8; ++j) o[j] = t[kg * 8 + j][c];
    *reinterpret_cast<s8v*>(de + (size_t)gi * 8) = o;
  }
}

// ---------------- GEMM1: h[b,mt,s] = g * relu(x @ Wd[e_s] + bd) -> ht (bf16, tiled) ----------
// grid 512: bid = (mt*2+s)*8 + b. 64x256 tile, K=1024, 8 waves (2x4), dbuf, 2 blocks/CU.
__global__ __launch_bounds__(512, 4) void gemm1_kernel(
    const float* __restrict__ x, const float* __restrict__ bd,
    const short* __restrict__ Wdt, const float* __restrict__ gslot,
    const int* __restrict__ sel2, short* __restrict__ ht) {
  __shared__ short sA[2][4096];    // XOR-swizzled [r(64)][kg(8)x8] image, 8KB each
  __shared__ short sB[2][16384];   // [kg(8)][r(256)][j(8)] image, 32KB each

  const int bid = blockIdx.x;
  const int b = bid & 7, q = bid >> 3;
  const int mt = q >> 1, s = q & 1;
  const int e = sel2[b * 2 + s];
  const float g = gslot[b * 2 + s];
  const int tid = threadIdx.x, lane = tid & 63, wid = tid >> 6;
  const int wr = wid >> 2, wc = wid & 3, lr = lane & 15, lg = lane >> 4;
  const float* xb = x + ((size_t)b * Lc + mt * 64) * Hc;
  const short* wdt = Wdt + (size_t)e * (Rc * Hc);
  const int sr = tid >> 3, skg = tid & 7;
  const int aw_off = sr * 64 + ((skg * 8) ^ ((sr & 7) * 8));   // shorts

  f4v acc[2][4];
  #pragma unroll
  for (int m = 0; m < 2; ++m)
    #pragma unroll
    for (int n = 0; n < 4; ++n) { acc[m][n][0]=0.f; acc[m][n][1]=0.f; acc[m][n][2]=0.f; acc[m][n][3]=0.f; }

  // prologue: stage kt=0
  {
    const short* gsrc = wdt;      // kt=0
    #pragma unroll
    for (int p = 0; p < 4; ++p)
      gload_lds16(gsrc + (p * 512 + tid) * 8, &sB[0][(p * 512 + tid) * 8]);
    f4v v0 = *reinterpret_cast<const f4v*>(xb + (size_t)sr * Hc + skg * 8);
    f4v v1 = *reinterpret_cast<const f4v*>(xb + (size_t)sr * Hc + skg * 8 + 4);
    s8v o;
    o[0]=(short)f2bf(v0[0]); o[1]=(short)f2bf(v0[1]); o[2]=(short)f2bf(v0[2]); o[3]=(short)f2bf(v0[3]);
    o[4]=(short)f2bf(v1[0]); o[5]=(short)f2bf(v1[1]); o[6]=(short)f2bf(v1[2]); o[7]=(short)f2bf(v1[3]);
    *reinterpret_cast<s8v*>(&sA[0][aw_off]) = o;
  }
  __syncthreads();

  for (int kt = 0; kt < 16; ++kt) {
    const int cur = kt & 1, nxt = cur ^ 1;
    f4v nv0, nv1;
    if (kt < 15) {
      const short* gsrc = wdt + (kt + 1) * 16384;
      #pragma unroll
      for (int p = 0; p < 4; ++p)
        gload_lds16(gsrc + (p * 512 + tid) * 8, &sB[nxt][(p * 512 + tid) * 8]);
      nv0 = *reinterpret_cast<const f4v*>(xb + (size_t)sr * Hc + (kt + 1) * 64 + skg * 8);
      nv1 = *reinterpret_cast<const f4v*>(xb + (size_t)sr * Hc + (kt + 1) * 64 + skg * 8 + 4);
    }
    #pragma unroll
    for (int kk = 0; kk < 2; ++kk) {
      s8v af[2], bf[4];
      #pragma unroll
      for (int m = 0; m < 2; ++m) {
        int r = wr * 32 + m * 16 + lr;
        af[m] = *reinterpret_cast<const s8v*>(&sA[cur][r * 64 + (((kk * 4 + lg) * 8) ^ ((r & 7) * 8))]);
      }
      #pragma unroll
      for (int n = 0; n < 4; ++n) {
        int c = wc * 64 + n * 16 + lr;
        bf[n] = *reinterpret_cast<const s8v*>(&sB[cur][((kk * 4 + lg) * 256 + c) * 8]);
      }
      #pragma unroll
      for (int m = 0; m < 2; ++m)
        #pragma unroll
        for (int n = 0; n < 4; ++n)
          acc[m][n] = __builtin_amdgcn_mfma_f32_16x16x32_bf16(af[m], bf[n], acc[m][n], 0, 0, 0);
    }
    if (kt < 15) {
      s8v o;
      o[0]=(short)f2bf(nv0[0]); o[1]=(short)f2bf(nv0[1]); o[2]=(short)f2bf(nv0[2]); o[3]=(short)f2bf(nv0[3]);
      o[4]=(short)f2bf(nv1[0]); o[5]=(short)f2bf(nv1[1]); o[6]=(short)f2bf(nv1[2]); o[7]=(short)f2bf(nv1[3]);
      *reinterpret_cast<s8v*>(&sA[nxt][aw_off]) = o;
    }
    __syncthreads();
  }

  // epilogue: bias + relu + gate, repack to GEMM2 A-image, write ht
  short* rp = &sB[0][0];   // 16384 shorts, safe after final barrier
  const float* bde = bd + e * Rc;
  #pragma unroll
  for (int n = 0; n < 4; ++n) {
    int c = wc * 64 + n * 16 + lr;
    float bdv = bde[c];
    #pragma unroll
    for (int m = 0; m < 2; ++m)
      #pragma unroll
      for (int i = 0; i < 4; ++i) {
        int rr = wr * 32 + m * 16 + lg * 4 + i;
        float vv = fmaxf(acc[m][n][i] + bdv, 0.f) * g;
        rp[((c >> 3) * 64 + rr) * 8 + (c & 7)] = (short)f2bf(vv);
      }
  }
  __syncthreads();
  const int mt2 = mt >> 1, rbase = (mt & 1) * 64;
  short* hb = ht + (((size_t)b * 16 + mt2) * 8 + s * 4) * 8192;
  #pragma unroll
  for (int p = 0; p < 4; ++p) {
    int gi = p * 512 + tid;
    int ftl = gi >> 9, kg = (gi >> 6) & 7, rr = gi & 63;
    s8v v = *reinterpret_cast<const s8v*>(&rp[gi * 8]);
    *reinterpret_cast<s8v*>(hb + (((size_t)ftl * 8 + kg) * 128 + rbase + rr) * 8) = v;
  }
}

// ---------------- GEMM2: out = x + h_concat @ Wu_concat + sum g*bu ----------------
// grid 1024: bid = ((mt2*8+nt))*8 + b. 128x128 tile, K=512 (2 experts concat), dbuf, 2 blocks/CU.
__global__ __launch_bounds__(512, 4) void gemm2_kernel(
    const float* __restrict__ x, const float* __restrict__ bu,
    const short* __restrict__ ht, const short* __restrict__ Wut2,
    const float* __restrict__ gslot, const int* __restrict__ sel2,
    float* __restrict__ out) {
  __shared__ short sA[2][8192];   // [kg(8)][r(128)][j(8)]
  __shared__ short sB[2][8192];   // [kg(8)][c(128)][j(8)]

  const int bid = blockIdx.x;
  const int b = bid & 7, q = bid >> 3;
  const int mt2 = q >> 3, nt = q & 7;
  const int e0 = sel2[b * 2], e1 = sel2[b * 2 + 1];
  const float g0 = gslot[b * 2], g1 = gslot[b * 2 + 1];
  const int tid = threadIdx.x, lane = tid & 63, wid = tid >> 6;
  const int wr = wid >> 2, wc = wid & 3, lr = lane & 15, lg = lane >> 4;
  const short* ab = ht + ((size_t)b * 16 + mt2) * 65536;

  f4v acc[4][2];
  #pragma unroll
  for (int m = 0; m < 4; ++m)
    #pragma unroll
    for (int n = 0; n < 2; ++n) { acc[m][n][0]=0.f; acc[m][n][1]=0.f; acc[m][n][2]=0.f; acc[m][n][3]=0.f; }

  // prologue: stage ft=0
  {
    const short* ga = ab;
    const short* gb = Wut2 + (((size_t)e0 * 8 + nt) * 4 + 0) * 8192;
    #pragma unroll
    for (int p = 0; p < 2; ++p) {
      gload_lds16(ga + (p * 512 + tid) * 8, &sA[0][(p * 512 + tid) * 8]);
      gload_lds16(gb + (p * 512 + tid) * 8, &sB[0][(p * 512 + tid) * 8]);
    }
  }
  __syncthreads();

  for (int ft = 0; ft < 8; ++ft) {
    const int cur = ft & 1, nxt = cur ^ 1;
    if (ft < 7) {
      const int f2 = ft + 1;
      const short* ga = ab + f2 * 8192;
      const int ee = (f2 < 4) ? e0 : e1;
      const short* gb = Wut2 + (((size_t)ee * 8 + nt) * 4 + (f2 & 3)) * 8192;
      #pragma unroll
      for (int p = 0; p < 2; ++p) {
        gload_lds16(ga + (p * 512 + tid) * 8, &sA[nxt][(p * 512 + tid) * 8]);
        gload_lds16(gb + (p * 512 + tid) * 8, &sB[nxt][(p * 512 + tid) * 8]);
      }
    }
    #pragma unroll
    for (int kk = 0; kk < 2; ++kk) {
      s8v af[4], bf[2];
      #pragma unroll
      for (int m = 0; m < 4; ++m) {
        int r = wr * 64 + m * 16 + lr;
        af[m] = *reinterpret_cast<const s8v*>(&sA[cur][((kk * 4 + lg) * 128 + r) * 8]);
      }
      #pragma unroll
      for (int n = 0; n < 2; ++n) {
        int c = wc * 32 + n * 16 + lr;
        bf[n] = *reinterpret_cast<const s8v*>(&sB[cur][((kk * 4 + lg) * 128 + c) * 8]);
      }
      #pragma unroll
      for (int m = 0; m < 4; ++m)
        #pragma unroll
        for (int n = 0; n < 2; ++n)
          acc[m][n] = __builtin_amdgcn_mfma_f32_16x16x32_bf16(af[m], bf[n], acc[m][n], 0, 0, 0);
    }
    __syncthreads();
  }

  // epilogue: residual + gated up-bias
  const int R0 = mt2 * 128 + wr * 64, C0 = nt * 128 + wc * 32;
  #pragma unroll
  for (int n = 0; n < 2; ++n) {
    int C = C0 + n * 16 + lr;
    float bias = g0 * bu[e0 * Hc + C] + g1 * bu[e1 * Hc + C];
    #pragma unroll
    for (int m = 0; m < 4; ++m)
      #pragma unroll
      for (int i = 0; i < 4; ++i) {
        int R = R0 + m * 16 + lg * 4 + i;
        size_t idx = ((size_t)b * Lc + R) * Hc + C;
        out[idx] = x[idx] + acc[m][n][i] + bias;
      }
  }
}

extern "C" void kernel_launch(void* const* d_in, const int* in_sizes, int n_in,
                              void* d_out, int out_size, void* d_ws, size_t ws_size,
                              hipStream_t stream) {
  const float* x  = (const float*)d_in[0];
  const float* Wd = (const float*)d_in[1];
  const float* bd = (const float*)d_in[2];
  const float* Wu = (const float*)d_in[3];
  const float* bu = (const float*)d_in[4];
  const float* Wr = (const float*)d_in[5];
  const int* topk = (const int*)d_in[6];
  float* out = (float*)d_out;

  char* ws = (char*)d_ws;
  float* logits = (float*)ws;                          // 256 B
  float* gslot  = (float*)(ws + 1024);                 // 64 B
  int*   sel2   = (int*)(ws + 2048);                   // 64 B
  float* part   = (float*)(ws + 65536);                // 1 MB (8*32*1024 f32)
  char*  p1     = ws + 65536 + (size_t)Bc * 32 * Hc * 4;
  short* Wdt    = (short*)p1;                          // 4 MB  (E*H*R bf16, tiled)
  short* Wut2   = (short*)(p1 + (size_t)Ec * Hc * Rc * 2);   // 4 MB (tiled)
  short* ht     = (short*)(p1 + (size_t)Ec * Hc * Rc * 4);   // 16 MB (B*L*512 bf16, tiled)

  hipLaunchKernelGGL(pool_partial_kernel, dim3(Bc, 32), dim3(256), 0, stream, x, part);
  // Wd (E,1024,256): Rows=1024, Cols=256, CT=256, NRT=16, NCT=1
  hipLaunchKernelGGL((tile_weight_kernel<256>), dim3(Ec, 16, 1), dim3(256), 0, stream,
                     Wd, Wdt, Hc, Rc, 16, 1);
  // Wu (E,256,1024): Rows=256, Cols=1024, CT=128, NRT=4, NCT=8
  hipLaunchKernelGGL((tile_weight_kernel<128>), dim3(Ec, 4, 8), dim3(256), 0, stream,
                     Wu, Wut2, Rc, Hc, 4, 8);
  hipLaunchKernelGGL(logits_kernel, dim3(Bc * Ec), dim3(256), 0, stream, part, Wr, logits);
  hipLaunchKernelGGL(softmax_topk_kernel, dim3(1), dim3(64), 0, stream,
                     logits, topk, gslot, sel2);
  hipLaunchKernelGGL(gemm1_kernel, dim3(512), dim3(512), 0, stream,
                     x, bd, Wdt, gslot, sel2, ht);
  hipLaunchKernelGGL(gemm2_kernel, dim3(1024), dim3(512), 0, stream,
                     x, bu, ht, Wut2, gslot, sel2, out);
}